// Round 6
// baseline (365.078 us; speedup 1.0000x reference)
//
#include <hip/hip_runtime.h>
#include <stdint.h>

#define DM 4096

typedef __attribute__((ext_vector_type(4))) float f32x4;
typedef __attribute__((ext_vector_type(8))) short s16x8;
typedef __attribute__((ext_vector_type(8))) unsigned short u16x8;
typedef __attribute__((ext_vector_type(4))) unsigned short u16x4;

__device__ __forceinline__ unsigned short f2bf(float f) {
  union { float f; unsigned u; } c; c.f = f;
  unsigned u = c.u;
  u += 0x7FFFu + ((u >> 16) & 1u);   // round-to-nearest-even
  return (unsigned short)(u >> 16);
}
__device__ __forceinline__ float bf2f(unsigned short h) {
  union { unsigned u; float f; } c; c.u = ((unsigned)h) << 16;
  return c.f;
}

// split fp32 -> bf16 hi (truncated) + bf16 lo (RNE of residual)
__device__ __forceinline__ void splitbf(float v, short& hi, short& lo) {
  union { float f; unsigned u; } c; c.f = v;
  unsigned uh = c.u & 0xFFFF0000u;
  hi = (short)(uh >> 16);
  union { unsigned u; float f; } d; d.u = uh;
  lo = (short)f2bf(v - d.f);
}

// ---------- kernel 0: x (128x4096 f32) -> blocked bf16 hi plane ----------
// layout: xh[kg][s][e], kg in [0,512), s in [0,128), e in [0,8): x[s][kg*8+e]
__global__ __launch_bounds__(256) void k0_xsplit(const float* __restrict__ x,
                                                 unsigned short* __restrict__ xh) {
  int g = blockIdx.x * 256 + threadIdx.x;  // 65536 threads
  int kg = g & 511, s = g >> 9;
  const float* px = x + (size_t)s * DM + kg * 8;
  f32x4 v0 = *(const f32x4*)px;
  f32x4 v1 = *(const f32x4*)(px + 4);
  u16x8 hi;
#pragma unroll
  for (int j = 0; j < 8; ++j) {
    float v = (j < 4) ? v0[j] : v1[j - 4];
    hi[j] = f2bf(v);
  }
  *(u16x8*)(xh + ((size_t)kg * 128 + s) * 8) = hi;
}

// ---------- kernel 1: proj partials = W_all . x^T (split-K=2) ----------
// NO LDS, NO barriers. grid 384 = 192 rowblocks x 2 kc; 4 waves x 16 rows.
// A: 256-float supersteps, register ring depth 2 (16 KB in flight per wave).
// B: per-lane MFMA fragments loaded DIRECT from blocked xh (L1/L2-resident),
//    register ring depth 2 at substep level.
// stores fp32 partials pp[(kc*3+w)*524288 + off]:
//   w in {Q,K}: off = (h*128 + s)*128 + d   | w == V: off = (h*128 + d)*128 + s
__global__ __launch_bounds__(256, 2) void k1_proj(const float* __restrict__ Q,
                                                  const float* __restrict__ K,
                                                  const float* __restrict__ V,
                                                  const unsigned short* __restrict__ xh,
                                                  float* __restrict__ pp) {
  int bid = blockIdx.x;
  int rb = bid >> 1, kc = bid & 1;
  int r0 = rb * 64;
  int w = r0 >> 12;        // 0:Q 1:K 2:V
  int rloc = r0 & 4095;
  const float* W = (w == 0) ? Q : ((w == 1) ? K : V);
  int tid = threadIdx.x;
  int wave = tid >> 6, lane = tid & 63;
  int l15 = lane & 15, lg = lane >> 4;
  int rwb = rloc + wave * 16;
  const float* arow = W + (size_t)(rwb + l15) * DM + lg * 8;
  const s16x8* xb = (const s16x8*)xh;
  int kbase = kc * 2048;

  f32x4 acc[8];
#pragma unroll
  for (int i = 0; i < 8; ++i) acc[i] = (f32x4)0.f;
  f32x4 aRA[16], aRB[16];
  s16x8 bfA[8], bfB[8];

  auto loadA = [&](f32x4* aR, int kss) {
#pragma unroll
    for (int u = 0; u < 8; ++u) {
      aR[2 * u] = *(const f32x4*)(arow + kss + u * 32);
      aR[2 * u + 1] = *(const f32x4*)(arow + kss + u * 32 + 4);
    }
  };
  auto loadB = [&](s16x8* bf, int kk) {
    const s16x8* bp = xb + ((size_t)(kk >> 3) + lg) * 128;
#pragma unroll
    for (int nt = 0; nt < 8; ++nt) bf[nt] = bp[nt * 16 + l15];
  };
  auto sub = [&](const f32x4& a0, const f32x4& a1, s16x8* bf) {
    s16x8 Ahi, Alo;
#pragma unroll
    for (int j = 0; j < 8; ++j) {
      float v = (j < 4) ? a0[j] : a1[j - 4];
      short hh, ll; splitbf(v, hh, ll);
      Ahi[j] = hh; Alo[j] = ll;
    }
#pragma unroll
    for (int nt = 0; nt < 8; ++nt) {
      acc[nt] = __builtin_amdgcn_mfma_f32_16x16x32_bf16(Ahi, bf[nt], acc[nt], 0, 0, 0);
      acc[nt] = __builtin_amdgcn_mfma_f32_16x16x32_bf16(Alo, bf[nt], acc[nt], 0, 0, 0);
    }
  };
  // one superstep = 8 substeps of K=32; prefetches next A superstep + B ring
  auto superstep = [&](f32x4* aCur, f32x4* aNxt, int kss, int kssNxt) {
    if (kssNxt >= 0) loadA(aNxt, kssNxt);
#pragma unroll
    for (int u = 0; u < 8; ++u) {
      s16x8* bc = (u & 1) ? bfB : bfA;
      s16x8* bn = (u & 1) ? bfA : bfB;
      int kkB = (u < 7) ? (kss + (u + 1) * 32) : (kssNxt >= 0 ? kssNxt : kss);
      loadB(bn, kkB);
      sub(aCur[2 * u], aCur[2 * u + 1], bc);
    }
  };

  loadA(aRA, kbase);
  loadB(bfA, kbase);
  for (int sp = 0; sp < 4; ++sp) {
    int k0s = kbase + sp * 512;
    superstep(aRA, aRB, k0s, k0s + 256);
    superstep(aRB, aRA, k0s + 256, (sp < 3) ? (k0s + 512) : -1);
  }

  int h = rwb >> 7;
  int dbase = (rwb & 127) + (lg << 2);
  size_t base = (size_t)(kc * 3 + w) * 524288;
  if (w < 2) {
#pragma unroll
    for (int nt = 0; nt < 8; ++nt) {
      int s = nt * 16 + l15;
      *(f32x4*)(pp + base + (size_t)(h * 128 + s) * 128 + dbase) = acc[nt];
    }
  } else {
#pragma unroll
    for (int nt = 0; nt < 8; ++nt) {
      int s = nt * 16 + l15;
#pragma unroll
      for (int r = 0; r < 4; ++r)
        pp[base + (size_t)(h * 128 + dbase + r) * 128 + s] = acc[nt][r];
    }
  }
}

// ---------- kernel 2: per-head attention, q split 4-way ----------
// grid 128 = 32 heads x 4 q-quarters; block 128 = 2 waves, wave owns 16 q.
// LDS 64KB: Kb blocked [dg16][k128][8] at shorts [0,16384); Vb blocked
// [kg16][d128][8] at [16384,32768); P ([kg16][q32][8], 8KB) aliases Kb.
// att output BLOCKED: attb[j/8][c128][8], j = h*128+q, c = d.
__global__ __launch_bounds__(128) void k2_attn(const float* __restrict__ pp,
                                               unsigned short* __restrict__ att) {
  __shared__ __align__(16) unsigned short lds[32768];
  int bid = blockIdx.x;
  int h = bid >> 2, qq = bid & 3;
  int tid = threadIdx.x, wave = tid >> 6, lane = tid & 63;
  int l15 = lane & 15, lg = lane >> 4;
  const float* pk0 = pp + (size_t)1 * 524288 + (size_t)h * 16384;
  const float* pk1 = pp + (size_t)4 * 524288 + (size_t)h * 16384;
  const float* pv0 = pp + (size_t)2 * 524288 + (size_t)h * 16384;
  const float* pv1 = pp + (size_t)5 * 524288 + (size_t)h * 16384;
  for (int g = tid; g < 2048; g += 128) {
    int dg = g & 15, k = g >> 4;
    size_t so = (size_t)k * 128 + dg * 8;
    f32x4 u0 = *(const f32x4*)(pk0 + so);
    f32x4 u1 = *(const f32x4*)(pk0 + so + 4);
    f32x4 w0 = *(const f32x4*)(pk1 + so);
    f32x4 w1 = *(const f32x4*)(pk1 + so + 4);
    u16x8 kb;
#pragma unroll
    for (int j = 0; j < 4; ++j) {
      kb[j] = f2bf(u0[j] + w0[j]);
      kb[4 + j] = f2bf(u1[j] + w1[j]);
    }
    *(u16x8*)&lds[(size_t)(dg * 128 + k) * 8] = kb;
    int kg = g & 15, d = g >> 4;
    size_t vo = (size_t)d * 128 + kg * 8;
    f32x4 x0 = *(const f32x4*)(pv0 + vo);
    f32x4 x1 = *(const f32x4*)(pv0 + vo + 4);
    f32x4 y0 = *(const f32x4*)(pv1 + vo);
    f32x4 y1 = *(const f32x4*)(pv1 + vo + 4);
    u16x8 vb;
#pragma unroll
    for (int j = 0; j < 4; ++j) {
      vb[j] = f2bf(x0[j] + y0[j]);
      vb[4 + j] = f2bf(x1[j] + y1[j]);
    }
    *(u16x8*)&lds[16384 + (size_t)(kg * 128 + d) * 8] = vb;
  }
  __syncthreads();

  int qbase = qq * 32 + wave * 16;
  const float* pq0 = pp + (size_t)h * 16384;
  const float* pq1 = pp + (size_t)3 * 524288 + (size_t)h * 16384;
  const float RS = 0.08838834764831845f;  // 1/sqrt(128)
  f32x4 sc[8];
#pragma unroll
  for (int b = 0; b < 8; ++b) sc[b] = (f32x4)0.f;

  for (int ks = 0; ks < 4; ++ks) {
    s16x8 qhi, qlo;
    {
      int q = qbase + l15;
      size_t qo = (size_t)q * 128 + ks * 32 + lg * 8;
      f32x4 u0 = *(const f32x4*)(pq0 + qo);
      f32x4 u1 = *(const f32x4*)(pq0 + qo + 4);
      f32x4 w0 = *(const f32x4*)(pq1 + qo);
      f32x4 w1 = *(const f32x4*)(pq1 + qo + 4);
#pragma unroll
      for (int j = 0; j < 8; ++j) {
        float v = ((j < 4) ? (u0[j] + w0[j]) : (u1[j - 4] + w1[j - 4])) * RS;
        unsigned short hh = f2bf(v);
        qhi[j] = (short)hh;
        qlo[j] = (short)f2bf(v - bf2f(hh));
      }
    }
#pragma unroll
    for (int nt = 0; nt < 8; ++nt) {
      s16x8 kb = *(const s16x8*)&lds[(size_t)((ks * 4 + lg) * 128 + nt * 16 + l15) * 8];
      sc[nt] = __builtin_amdgcn_mfma_f32_16x16x32_bf16(qhi, kb, sc[nt], 0, 0, 0);
      sc[nt] = __builtin_amdgcn_mfma_f32_16x16x32_bf16(qlo, kb, sc[nt], 0, 0, 0);
    }
  }
  // masked softmax (keep k >= q), row distributed over 16 lanes x 8 ntiles
  float inv[4];
#pragma unroll
  for (int r = 0; r < 4; ++r) {
    int q = qbase + (lg << 2) + r;
    float m = -3.0e38f;
#pragma unroll
    for (int nt = 0; nt < 8; ++nt) {
      int k = nt * 16 + l15;
      float v = sc[nt][r];
      if (k >= q) m = fmaxf(m, v);
    }
#pragma unroll
    for (int d = 1; d < 16; d <<= 1) m = fmaxf(m, __shfl_xor(m, d));
    float ssum = 0.f;
#pragma unroll
    for (int nt = 0; nt < 8; ++nt) {
      int k = nt * 16 + l15;
      float v = sc[nt][r];
      float e = (k >= q) ? __expf(v - m) : 0.f;
      sc[nt][r] = e;
      ssum += e;
    }
#pragma unroll
    for (int d = 1; d < 16; d <<= 1) ssum += __shfl_xor(ssum, d);
    inv[r] = 1.f / ssum;
  }
  __syncthreads();  // all waves done reading Kb
  // write P (alias Kb): blocked [k/8][relq32][k%8]
#pragma unroll
  for (int nt = 0; nt < 8; ++nt) {
    int k = nt * 16 + l15;
#pragma unroll
    for (int r = 0; r < 4; ++r) {
      int relq = wave * 16 + (lg << 2) + r;
      lds[(size_t)((k >> 3) * 32 + relq) * 8 + (k & 7)] = f2bf(sc[nt][r] * inv[r]);
    }
  }
  __syncthreads();
  // PV
  f32x4 o[8];
#pragma unroll
  for (int b = 0; b < 8; ++b) o[b] = (f32x4)0.f;
  for (int ks = 0; ks < 4; ++ks) {
    s16x8 pa = *(const s16x8*)&lds[(size_t)((ks * 4 + lg) * 32 + wave * 16 + l15) * 8];
#pragma unroll
    for (int nt = 0; nt < 8; ++nt) {
      s16x8 vb = *(const s16x8*)&lds[16384 + (size_t)((ks * 4 + lg) * 128 + nt * 16 + l15) * 8];
      o[nt] = __builtin_amdgcn_mfma_f32_16x16x32_bf16(pa, vb, o[nt], 0, 0, 0);
    }
  }
  // store att blocked: attb[(j>>3)*1024 + c*8 + (j&7)], j = h*128+q, c = d
#pragma unroll
  for (int nt = 0; nt < 8; ++nt) {
    int c = nt * 16 + l15;
    int jq = h * 128 + qbase + (lg << 2);
    u16x4 pk;
#pragma unroll
    for (int r = 0; r < 4; ++r) pk[r] = f2bf(o[nt][r]);
    *(u16x4*)(att + (size_t)(jq >> 3) * 1024 + c * 8 + (jq & 7)) = pk;
  }
}

// ---------- kernel 3: out += O @ att (split-K=8, no-LDS burst pipeline) -----
// grid 512 = 64 rowblocks x 8 kc; block 256 = 4 waves, wave owns 16 rows.
__global__ __launch_bounds__(256, 2) void k3_out(const float* __restrict__ O,
                                                 const unsigned short* __restrict__ att,
                                                 float* __restrict__ out) {
  int bid = blockIdx.x;
  int rb = bid >> 3, kc = bid & 7;
  int r0 = rb * 64;
  int kbase = kc * 512;
  int tid = threadIdx.x, wave = tid >> 6, lane = tid & 63;
  int l15 = lane & 15, lg = lane >> 4;
  int rwb = r0 + wave * 16;
  const float* arow = O + (size_t)(rwb + l15) * DM + lg * 8;
  const s16x8* ab = (const s16x8*)att;

  f32x4 acc[8];
#pragma unroll
  for (int i = 0; i < 8; ++i) acc[i] = (f32x4)0.f;
  f32x4 aRA[16], aRB[16];
  s16x8 bfA[8], bfB[8];

  auto loadA = [&](f32x4* aR, int kss) {
#pragma unroll
    for (int u = 0; u < 8; ++u) {
      aR[2 * u] = *(const f32x4*)(arow + kss + u * 32);
      aR[2 * u + 1] = *(const f32x4*)(arow + kss + u * 32 + 4);
    }
  };
  auto loadB = [&](s16x8* bf, int kk) {
    const s16x8* bp = ab + ((size_t)(kk >> 3) + lg) * 128;
#pragma unroll
    for (int nt = 0; nt < 8; ++nt) bf[nt] = bp[nt * 16 + l15];
  };
  auto sub = [&](const f32x4& a0, const f32x4& a1, s16x8* bf) {
    s16x8 Ahi, Alo;
#pragma unroll
    for (int j = 0; j < 8; ++j) {
      float v = (j < 4) ? a0[j] : a1[j - 4];
      short hh, ll; splitbf(v, hh, ll);
      Ahi[j] = hh; Alo[j] = ll;
    }
#pragma unroll
    for (int nt = 0; nt < 8; ++nt) {
      acc[nt] = __builtin_amdgcn_mfma_f32_16x16x32_bf16(Ahi, bf[nt], acc[nt], 0, 0, 0);
      acc[nt] = __builtin_amdgcn_mfma_f32_16x16x32_bf16(Alo, bf[nt], acc[nt], 0, 0, 0);
    }
  };
  auto superstep = [&](f32x4* aCur, f32x4* aNxt, int kss, int kssNxt) {
    if (kssNxt >= 0) loadA(aNxt, kssNxt);
#pragma unroll
    for (int u = 0; u < 8; ++u) {
      s16x8* bc = (u & 1) ? bfB : bfA;
      s16x8* bn = (u & 1) ? bfA : bfB;
      int kkB = (u < 7) ? (kss + (u + 1) * 32) : (kssNxt >= 0 ? kssNxt : kss);
      loadB(bn, kkB);
      sub(aCur[2 * u], aCur[2 * u + 1], bc);
    }
  };

  loadA(aRA, kbase);
  loadB(bfA, kbase);
  superstep(aRA, aRB, kbase, kbase + 256);
  superstep(aRB, aRA, kbase + 256, -1);

#pragma unroll
  for (int nt = 0; nt < 8; ++nt) {
#pragma unroll
    for (int r = 0; r < 4; ++r) {
      int row = rwb + (lg << 2) + r;
      atomicAdd(&out[(size_t)row * 128 + nt * 16 + l15], acc[nt][r]);
    }
  }
}

extern "C" void kernel_launch(void* const* d_in, const int* in_sizes, int n_in,
                              void* d_out, int out_size, void* d_ws, size_t ws_size,
                              hipStream_t stream) {
  const float* Q = (const float*)d_in[0];
  const float* K = (const float*)d_in[1];
  const float* V = (const float*)d_in[2];
  const float* O = (const float*)d_in[3];
  const float* x = (const float*)d_in[4];
  float* out = (float*)d_out;
  uint8_t* ws = (uint8_t*)d_ws;
  unsigned short* xh = (unsigned short*)ws;                        // 1 MB
  unsigned short* att = (unsigned short*)(ws + (1u << 20));        // 1 MB (blocked)
  float* pp = (float*)(ws + (2u << 20));                           // 12 MB
  hipMemsetAsync(d_out, 0, (size_t)out_size * sizeof(float), stream);
  hipLaunchKernelGGL(k0_xsplit, dim3(256), dim3(256), 0, stream, x, xh);
  hipLaunchKernelGGL(k1_proj, dim3(384), dim3(256), 0, stream, Q, K, V, xh, pp);
  hipLaunchKernelGGL(k2_attn, dim3(128), dim3(128), 0, stream, pp, att);
  hipLaunchKernelGGL(k3_out, dim3(512), dim3(256), 0, stream, O, att, out);
}

// Round 10
// 292.379 us; speedup vs baseline: 1.2486x; 1.2486x over previous
//
#include <hip/hip_runtime.h>
#include <stdint.h>

#define DM 4096

typedef __attribute__((ext_vector_type(4))) float f32x4;
typedef __attribute__((ext_vector_type(8))) short s16x8;
typedef __attribute__((ext_vector_type(8))) unsigned short u16x8;
typedef __attribute__((ext_vector_type(4))) unsigned short u16x4;

__device__ __forceinline__ unsigned short f2bf(float f) {
  union { float f; unsigned u; } c; c.f = f;
  unsigned u = c.u;
  u += 0x7FFFu + ((u >> 16) & 1u);   // round-to-nearest-even
  return (unsigned short)(u >> 16);
}
__device__ __forceinline__ float bf2f(unsigned short h) {
  union { unsigned u; float f; } c; c.u = ((unsigned)h) << 16;
  return c.f;
}
// split fp32 -> bf16 hi (truncated) + bf16 lo (RNE of residual)
__device__ __forceinline__ void splitbf(float v, short& hi, short& lo) {
  union { float f; unsigned u; } c; c.f = v;
  unsigned uh = c.u & 0xFFFF0000u;
  hi = (short)(uh >> 16);
  union { unsigned u; float f; } d; d.u = uh;
  lo = (short)f2bf(v - d.f);
}
// async global->LDS, 16B per lane; gsrc per-lane, ldst wave-uniform base
__device__ __forceinline__ void ld16(const void* gsrc, void* ldst) {
  __builtin_amdgcn_global_load_lds(
      (const __attribute__((address_space(1))) unsigned int*)gsrc,
      (__attribute__((address_space(3))) unsigned int*)ldst, 16, 0, 0);
}

// ---------- kernel 0: x (128x4096 f32) -> blocked bf16 plane ----------
// xh[kg][s][e]: kg in [0,512), s in [0,128), e in [0,8): x[s][kg*8+e]
__global__ __launch_bounds__(256) void k0_xsplit(const float* __restrict__ x,
                                                 unsigned short* __restrict__ xh) {
  int g = blockIdx.x * 256 + threadIdx.x;
  int kg = g & 511, s = g >> 9;
  const float* px = x + (size_t)s * DM + kg * 8;
  f32x4 v0 = *(const f32x4*)px;
  f32x4 v1 = *(const f32x4*)(px + 4);
  u16x8 hi;
#pragma unroll
  for (int j = 0; j < 8; ++j) hi[j] = f2bf((j < 4) ? v0[j] : v1[j - 4]);
  *(u16x8*)(xh + ((size_t)kg * 128 + s) * 8) = hi;
}

// ---------- kernel 1: proj partials (bf16) = W_all . x^T, split-K=4 ----------
// m97-style: double-buffered LDS, global_load_lds staging, 2-phase barrier loop.
// grid 768 = 192 rowblocks x 4 kc; block 256 = 4 waves x 16 rows.
// A LDS tile 64r x 32k fp32, XOR-swizzled (granule ^ (row&7)) via pre-swizzled
// global source. B = xh blocked, staged linearly.
// pp slots (bf16, 524288 each), slot = kc*3+w:
//   w in {Q,K}: off=(h*128+s)*128+d | w==V: off=(h*128+d)*128+s
__global__ __launch_bounds__(256) void k1_proj(const float* __restrict__ Q,
                                               const float* __restrict__ K,
                                               const float* __restrict__ V,
                                               const unsigned short* __restrict__ xh,
                                               unsigned short* __restrict__ pp) {
  __shared__ __align__(16) float Abuf[2][2048];          // 2 x 8KB
  __shared__ __align__(16) unsigned short Bbuf[2][4096]; // 2 x 8KB
  int bid = blockIdx.x;
  int rb = bid >> 2, kc = bid & 3;
  int r0 = rb * 64;
  int w = r0 >> 12;        // 0:Q 1:K 2:V
  int rloc = r0 & 4095;    // LOCAL row base within the selected matrix
  const float* W = (w == 0) ? Q : ((w == 1) ? K : V);
  int tid = threadIdx.x;
  int wave = tid >> 6, lane = tid & 63;
  int l15 = lane & 15, lg = lane >> 4;
  int kbase = kc * 1024;

  // staging geometry (per wave: 2 A-instrs + 2 B-instrs of 1KB each)
  int i8 = lane >> 3, sg = lane & 7;            // A: row-sub, slot granule
  int swg = sg ^ i8;                            // pre-swizzled source granule
  auto stage = [&](int buf, int kk) {
#pragma unroll
    for (int jj = 0; jj < 2; ++jj) {
      int j = wave * 2 + jj;                    // A instr j: rows j*8..+8
      int r = j * 8 + i8;
      ld16(W + (size_t)(rloc + r) * DM + kk + swg * 4, &Abuf[buf][j * 256]);
    }
#pragma unroll
    for (int jj = 0; jj < 2; ++jj) {
      int j = wave * 2 + jj;                    // B instr j: 512 ushorts
      ld16(xh + (size_t)(kk >> 3) * 1024 + j * 512 + lane * 8, &Bbuf[buf][j * 512]);
    }
  };

  f32x4 acc[8];
#pragma unroll
  for (int i = 0; i < 8; ++i) acc[i] = (f32x4)0.f;

  stage(0, kbase);
  __syncthreads();
  int cur = 0;
  for (int t = 0; t < 32; ++t) {
    if (t < 31) stage(cur ^ 1, kbase + (t + 1) * 32);
    // A fragment from swizzled LDS
    int r = wave * 16 + l15;
    int s0 = (lg * 2) ^ (l15 & 7);
    int s1 = (lg * 2 + 1) ^ (l15 & 7);
    f32x4 a0 = *(const f32x4*)&Abuf[cur][r * 32 + s0 * 4];
    f32x4 a1 = *(const f32x4*)&Abuf[cur][r * 32 + s1 * 4];
    s16x8 Ahi, Alo;
#pragma unroll
    for (int j = 0; j < 8; ++j) {
      float v = (j < 4) ? a0[j] : a1[j - 4];
      short hh, ll; splitbf(v, hh, ll);
      Ahi[j] = hh; Alo[j] = ll;
    }
#pragma unroll
    for (int nt = 0; nt < 8; ++nt) {
      s16x8 bh = *(const s16x8*)&Bbuf[cur][((lg * 128) + nt * 16 + l15) * 8];
      acc[nt] = __builtin_amdgcn_mfma_f32_16x16x32_bf16(Ahi, bh, acc[nt], 0, 0, 0);
      acc[nt] = __builtin_amdgcn_mfma_f32_16x16x32_bf16(Alo, bh, acc[nt], 0, 0, 0);
    }
    __syncthreads();
    cur ^= 1;
  }

  int rwb = rloc + wave * 16;
  int h = rwb >> 7;
  int dbase = (rwb & 127) + (lg << 2);
  size_t base = (size_t)(kc * 3 + w) * 524288;
  if (w < 2) {
#pragma unroll
    for (int nt = 0; nt < 8; ++nt) {
      int s = nt * 16 + l15;
      u16x4 pk;
#pragma unroll
      for (int r = 0; r < 4; ++r) pk[r] = f2bf(acc[nt][r]);
      *(u16x4*)(pp + base + (size_t)(h * 128 + s) * 128 + dbase) = pk;
    }
  } else {
#pragma unroll
    for (int nt = 0; nt < 8; ++nt) {
      int s = nt * 16 + l15;
#pragma unroll
      for (int r = 0; r < 4; ++r)
        pp[base + (size_t)(h * 128 + dbase + r) * 128 + s] = f2bf(acc[nt][r]);
    }
  }
}

// ---------- kernel 2: per-head attention, q split 4-way ----------
// grid 128 = 32 heads x 4 q-quarters; block 128 = 2 waves, wave owns 16 q.
// Sums 4 bf16 partial slots. LDS: Kb [dg16][k128][8] at [0,16384); Vb
// [kg16][d128][8] at [16384,32768); P ([kg][q32][8]) aliases Kb.
// att output BLOCKED: attb[j/8][c128][j%8], j = h*128+q, c = d.
__global__ __launch_bounds__(128) void k2_attn(const unsigned short* __restrict__ pp,
                                               unsigned short* __restrict__ att) {
  __shared__ __align__(16) unsigned short lds[32768];
  int bid = blockIdx.x;
  int h = bid >> 2, qq = bid & 3;
  int tid = threadIdx.x, wave = tid >> 6, lane = tid & 63;
  int l15 = lane & 15, lg = lane >> 4;
  const unsigned short* pk[4];
  const unsigned short* pv[4];
  const unsigned short* pq[4];
#pragma unroll
  for (int c = 0; c < 4; ++c) {
    pq[c] = pp + (size_t)(c * 3 + 0) * 524288 + (size_t)h * 16384;
    pk[c] = pp + (size_t)(c * 3 + 1) * 524288 + (size_t)h * 16384;
    pv[c] = pp + (size_t)(c * 3 + 2) * 524288 + (size_t)h * 16384;
  }
#pragma unroll 4
  for (int it = 0; it < 16; ++it) {
    int g = it * 128 + tid;
    int dg = g & 15, k = g >> 4;
    size_t so = (size_t)k * 128 + dg * 8;
    u16x8 l0 = *(const u16x8*)(pk[0] + so);
    u16x8 l1 = *(const u16x8*)(pk[1] + so);
    u16x8 l2 = *(const u16x8*)(pk[2] + so);
    u16x8 l3 = *(const u16x8*)(pk[3] + so);
    u16x8 kb;
#pragma unroll
    for (int j = 0; j < 8; ++j)
      kb[j] = f2bf(bf2f(l0[j]) + bf2f(l1[j]) + bf2f(l2[j]) + bf2f(l3[j]));
    *(u16x8*)&lds[(size_t)(dg * 128 + k) * 8] = kb;
    u16x8 m0 = *(const u16x8*)(pv[0] + so);
    u16x8 m1 = *(const u16x8*)(pv[1] + so);
    u16x8 m2 = *(const u16x8*)(pv[2] + so);
    u16x8 m3 = *(const u16x8*)(pv[3] + so);
    u16x8 vb;
#pragma unroll
    for (int j = 0; j < 8; ++j)
      vb[j] = f2bf(bf2f(m0[j]) + bf2f(m1[j]) + bf2f(m2[j]) + bf2f(m3[j]));
    *(u16x8*)&lds[16384 + (size_t)(dg * 128 + k) * 8] = vb;   // Vb[kg=dg][d=k][8]
  }
  __syncthreads();

  int qbase = qq * 32 + wave * 16;
  const float RS = 0.08838834764831845f;  // 1/sqrt(128)
  f32x4 sc[8];
#pragma unroll
  for (int b = 0; b < 8; ++b) sc[b] = (f32x4)0.f;

  for (int ks = 0; ks < 4; ++ks) {
    s16x8 qhi, qlo;
    {
      int q = qbase + l15;
      size_t qo = (size_t)q * 128 + ks * 32 + lg * 8;
      u16x8 q0 = *(const u16x8*)(pq[0] + qo);
      u16x8 q1 = *(const u16x8*)(pq[1] + qo);
      u16x8 q2 = *(const u16x8*)(pq[2] + qo);
      u16x8 q3 = *(const u16x8*)(pq[3] + qo);
#pragma unroll
      for (int j = 0; j < 8; ++j) {
        float v = (bf2f(q0[j]) + bf2f(q1[j]) + bf2f(q2[j]) + bf2f(q3[j])) * RS;
        short hh, ll; splitbf(v, hh, ll);
        qhi[j] = hh; qlo[j] = ll;
      }
    }
#pragma unroll
    for (int nt = 0; nt < 8; ++nt) {
      s16x8 kb = *(const s16x8*)&lds[(size_t)((ks * 4 + lg) * 128 + nt * 16 + l15) * 8];
      sc[nt] = __builtin_amdgcn_mfma_f32_16x16x32_bf16(qhi, kb, sc[nt], 0, 0, 0);
      sc[nt] = __builtin_amdgcn_mfma_f32_16x16x32_bf16(qlo, kb, sc[nt], 0, 0, 0);
    }
  }
  // masked softmax (keep k >= q)
  float inv[4];
#pragma unroll
  for (int r = 0; r < 4; ++r) {
    int q = qbase + (lg << 2) + r;
    float m = -3.0e38f;
#pragma unroll
    for (int nt = 0; nt < 8; ++nt) {
      int k = nt * 16 + l15;
      if (k >= q) m = fmaxf(m, sc[nt][r]);
    }
#pragma unroll
    for (int d = 1; d < 16; d <<= 1) m = fmaxf(m, __shfl_xor(m, d));
    float ssum = 0.f;
#pragma unroll
    for (int nt = 0; nt < 8; ++nt) {
      int k = nt * 16 + l15;
      float e = (k >= q) ? __expf(sc[nt][r] - m) : 0.f;
      sc[nt][r] = e;
      ssum += e;
    }
#pragma unroll
    for (int d = 1; d < 16; d <<= 1) ssum += __shfl_xor(ssum, d);
    inv[r] = 1.f / ssum;
  }
  __syncthreads();
  // write P (alias Kb): blocked [k/8][relq32][k%8]
#pragma unroll
  for (int nt = 0; nt < 8; ++nt) {
    int k = nt * 16 + l15;
#pragma unroll
    for (int r = 0; r < 4; ++r) {
      int relq = wave * 16 + (lg << 2) + r;
      lds[(size_t)((k >> 3) * 32 + relq) * 8 + (k & 7)] = f2bf(sc[nt][r] * inv[r]);
    }
  }
  __syncthreads();
  // PV
  f32x4 o[8];
#pragma unroll
  for (int b = 0; b < 8; ++b) o[b] = (f32x4)0.f;
  for (int ks = 0; ks < 4; ++ks) {
    s16x8 pa = *(const s16x8*)&lds[(size_t)((ks * 4 + lg) * 32 + wave * 16 + l15) * 8];
#pragma unroll
    for (int nt = 0; nt < 8; ++nt) {
      s16x8 vb = *(const s16x8*)&lds[16384 + (size_t)((ks * 4 + lg) * 128 + nt * 16 + l15) * 8];
      o[nt] = __builtin_amdgcn_mfma_f32_16x16x32_bf16(pa, vb, o[nt], 0, 0, 0);
    }
  }
  // store att blocked: attb[(j>>3)*1024 + c*8 + (j&7)], j = h*128+q, c = d
#pragma unroll
  for (int nt = 0; nt < 8; ++nt) {
    int c = nt * 16 + l15;
    int jq = h * 128 + qbase + (lg << 2);
    u16x4 pk4;
#pragma unroll
    for (int r = 0; r < 4; ++r) pk4[r] = f2bf(o[nt][r]);
    *(u16x4*)(att + (size_t)(jq >> 3) * 1024 + c * 8 + (jq & 7)) = pk4;
  }
}

// ---------- kernel 3: out += O @ att, split-K=8, m97-style (k1 twin) --------
// grid 512 = 64 rowblocks x 8 kc; block 256 = 4 waves x 16 rows; atomic out.
__global__ __launch_bounds__(256) void k3_out(const float* __restrict__ O,
                                              const unsigned short* __restrict__ att,
                                              float* __restrict__ out) {
  __shared__ __align__(16) float Abuf[2][2048];
  __shared__ __align__(16) unsigned short Bbuf[2][4096];
  int bid = blockIdx.x;
  int rb = bid >> 3, kc = bid & 7;
  int r0 = rb * 64;
  int tid = threadIdx.x;
  int wave = tid >> 6, lane = tid & 63;
  int l15 = lane & 15, lg = lane >> 4;
  int kbase = kc * 512;

  int i8 = lane >> 3, sg = lane & 7;
  int swg = sg ^ i8;
  auto stage = [&](int buf, int kk) {
#pragma unroll
    for (int jj = 0; jj < 2; ++jj) {
      int j = wave * 2 + jj;
      int r = j * 8 + i8;
      ld16(O + (size_t)(r0 + r) * DM + kk + swg * 4, &Abuf[buf][j * 256]);
    }
#pragma unroll
    for (int jj = 0; jj < 2; ++jj) {
      int j = wave * 2 + jj;
      ld16(att + (size_t)(kk >> 3) * 1024 + j * 512 + lane * 8, &Bbuf[buf][j * 512]);
    }
  };

  f32x4 acc[8];
#pragma unroll
  for (int i = 0; i < 8; ++i) acc[i] = (f32x4)0.f;

  stage(0, kbase);
  __syncthreads();
  int cur = 0;
  for (int t = 0; t < 16; ++t) {
    if (t < 15) stage(cur ^ 1, kbase + (t + 1) * 32);
    int r = wave * 16 + l15;
    int s0 = (lg * 2) ^ (l15 & 7);
    int s1 = (lg * 2 + 1) ^ (l15 & 7);
    f32x4 a0 = *(const f32x4*)&Abuf[cur][r * 32 + s0 * 4];
    f32x4 a1 = *(const f32x4*)&Abuf[cur][r * 32 + s1 * 4];
    s16x8 Ahi, Alo;
#pragma unroll
    for (int j = 0; j < 8; ++j) {
      float v = (j < 4) ? a0[j] : a1[j - 4];
      short hh, ll; splitbf(v, hh, ll);
      Ahi[j] = hh; Alo[j] = ll;
    }
#pragma unroll
    for (int nt = 0; nt < 8; ++nt) {
      s16x8 bh = *(const s16x8*)&Bbuf[cur][((lg * 128) + nt * 16 + l15) * 8];
      acc[nt] = __builtin_amdgcn_mfma_f32_16x16x32_bf16(Ahi, bh, acc[nt], 0, 0, 0);
      acc[nt] = __builtin_amdgcn_mfma_f32_16x16x32_bf16(Alo, bh, acc[nt], 0, 0, 0);
    }
    __syncthreads();
    cur ^= 1;
  }
#pragma unroll
  for (int nt = 0; nt < 8; ++nt) {
#pragma unroll
    for (int r = 0; r < 4; ++r) {
      int row = r0 + wave * 16 + (lg << 2) + r;
      atomicAdd(&out[(size_t)row * 128 + nt * 16 + l15], acc[nt][r]);
    }
  }
}

extern "C" void kernel_launch(void* const* d_in, const int* in_sizes, int n_in,
                              void* d_out, int out_size, void* d_ws, size_t ws_size,
                              hipStream_t stream) {
  const float* Q = (const float*)d_in[0];
  const float* K = (const float*)d_in[1];
  const float* V = (const float*)d_in[2];
  const float* O = (const float*)d_in[3];
  const float* x = (const float*)d_in[4];
  float* out = (float*)d_out;
  uint8_t* ws = (uint8_t*)d_ws;
  unsigned short* xh = (unsigned short*)ws;                  // 1 MB
  unsigned short* att = (unsigned short*)(ws + (1u << 20));  // 1 MB (blocked)
  unsigned short* pp = (unsigned short*)(ws + (2u << 20));   // 12 MB (bf16, 12 slots)
  hipMemsetAsync(d_out, 0, (size_t)out_size * sizeof(float), stream);
  hipLaunchKernelGGL(k0_xsplit, dim3(256), dim3(256), 0, stream, x, xh);
  hipLaunchKernelGGL(k1_proj, dim3(768), dim3(256), 0, stream, Q, K, V, xh, pp);
  hipLaunchKernelGGL(k2_attn, dim3(128), dim3(128), 0, stream, pp, att);
  hipLaunchKernelGGL(k3_out, dim3(512), dim3(256), 0, stream, O, att, out);
}